// Round 2
// baseline (13702.206 us; speedup 1.0000x reference)
//
#include <hip/hip_runtime.h>

// Persistent-kernel LSTM autoencoder for MI355X — round 5.
// Same structure as round 4 (8 groups x 2 WGs x 8 waves, register/AGPR-resident
// weights, LDS-staged halves, tagged-word exchange), with the exchange retuned
// for LATENCY: the pair {bid, bid+8} sits on the same XCD under round-robin, so
// the h-half exchange goes through the SHARED XCD L2 (sc0 store + sc0 poll,
// ~115ns hit) instead of the MALL (~400ns each way). A parallel sc0-sc1 store
// plus every-4th-retry sc0-sc1 poll keeps the protocol correct (no hang) if the
// scheduler places a pair across XCDs. Additionally the x-contribution MFMAs
// for step t+1 are software-pipelined into the poll-wait shadow.

typedef unsigned int u32;
typedef unsigned long long u64;
typedef unsigned short u16;

typedef _Float16 v8h __attribute__((ext_vector_type(8)));
typedef float    v4f __attribute__((ext_vector_type(4)));
typedef u32      v4u __attribute__((ext_vector_type(4)));

union H8 { v8h v; u64 q[2]; v4u u4; u32 d[4]; _Float16 h[8]; u16 s[8]; };

#define ENC_TAG(t) (0x4000u + (u32)(t))
#define DEC_TAG(t) (0x4800u + (u32)(t))
#define XW_OFF_U32   65536ull
#define XW_U32_PER_G 786432ull
#define WS_NEED ((XW_OFF_U32 + 8ull*XW_U32_PER_G) * 4ull)

static __device__ __forceinline__ float fsig(float x){
  return __builtin_amdgcn_rcpf(1.f + __builtin_amdgcn_exp2f(-1.4426950408889634f*x));
}
static __device__ __forceinline__ float ftanh(float x){
  return 1.f - 2.f*__builtin_amdgcn_rcpf(1.f + __builtin_amdgcn_exp2f(2.8853900817779268f*x));
}
static __device__ __forceinline__ u32 f2tag(float f, u32 tag){
  union{ _Float16 h; u16 b; } u; u.h = (_Float16)f;
  return (tag << 16) | (u32)u.b;
}

// Dual store: sc0 lands in the shared XCD L2 (fast path for a same-XCD
// reader); sc0+sc1 goes to the MALL (correctness for any placement).
static __device__ __forceinline__ void st_x2(u32* p, u32 val){
  asm volatile("global_store_dword %0, %1, off sc0\n\t"
               "global_store_dword %0, %1, off sc0 sc1" :: "v"(p), "v"(val) : "memory");
}
// Fast-path poll issue: L1-bypass read of the shared XCD L2.
static __device__ __forceinline__ void poll_issue(const u32* p, v4u& q){
  asm volatile("global_load_dwordx4 %0, %1, off sc0" : "=v"(q) : "v"(p) : "memory");
}
static __device__ __forceinline__ void poll_sc0(const u32* p, v4u& q){
  asm volatile("global_load_dwordx4 %0, %1, off sc0\n\ts_waitcnt vmcnt(0)"
               : "=v"(q) : "v"(p) : "memory");
}
static __device__ __forceinline__ void poll_sc01(const u32* p, v4u& q){
  asm volatile("global_load_dwordx4 %0, %1, off sc0 sc1\n\ts_waitcnt vmcnt(0)"
               : "=v"(q) : "v"(p) : "memory");
}
static __device__ __forceinline__ void poll_wait(v4u& q){
  asm volatile("s_waitcnt vmcnt(0)" : "+v"(q) :: "memory");
}

// Wait for tagged remote half-h words, then stage payload (4 x f16) into LDS.
// Retry pattern: tight sc0 polls (shared-L2 RTT ~300cy, no sleep); every 4th
// retry escalates to sc0-sc1 (MALL) + sleep so cross-XCD placement can't hang.
static __device__ __forceinline__ void poll_finish(const u32* p, u32 tag, v4u& q,
                                                   _Float16* dstbuf, int sbyte){
  const u32 tm = tag << 16;
  poll_wait(q);
  u32 it = 0;
  for(;;){
    u32 bad = (q[0]^tm)|(q[1]^tm)|(q[2]^tm)|(q[3]^tm);
    if (__all((bad & 0xFFFF0000u) == 0)) break;
    ++it;
    if ((it & 3u) == 0u){ __builtin_amdgcn_s_sleep(1); poll_sc01(p, q); }
    else                 poll_sc0(p, q);
  }
  u64 pk = (u64)(q[0]&0xFFFFu) | ((u64)(q[1]&0xFFFFu)<<16)
         | ((u64)(q[2]&0xFFFFu)<<32) | ((u64)(q[3]&0xFFFFu)<<48);
  *(u64*)((char*)dstbuf + sbyte) = pk;
}

// LDS A-fragment reads, XOR-swizzled (row*512B rows for h, row*256B for x/pred).
static __device__ __forceinline__ v4u frag_h(const _Float16* b, int row, int colh){
  const int a = (row*512 + colh*2) ^ ((row&7)<<4);
  return *(const v4u*)((const char*)b + a);
}
static __device__ __forceinline__ v4u frag_x(const _Float16* b, int row, int colh){
  const int a = (row*256 + colh*2) ^ ((row&7)<<4);
  return *(const v4u*)((const char*)b + a);
}

// B-frags: kt 0..2 = input (88+pad), kt 3..6 = LOCAL h half, kt 7..10 = REMOTE.
static __device__ __forceinline__ void build_Bw(v8h Bw[4][11], const float* Wih,
                                                const float* Whh, int wcol, int quad, int hf){
  #pragma unroll
  for (int nt = 0; nt < 4; ++nt){
    const int n = nt*256 + wcol;
    #pragma unroll
    for (int kt = 0; kt < 11; ++kt){
      H8 a;
      #pragma unroll
      for (int j = 0; j < 8; ++j){
        float val;
        if (kt < 3){
          const int k = kt*32 + quad*8 + j;
          val = (k < 88) ? Wih[n*88 + k] : 0.f;
        } else {
          const int base = (kt < 7) ? (hf*128 + (kt-3)*32) : ((1-hf)*128 + (kt-7)*32);
          val = Whh[n*256 + base + quad*8 + j];
        }
        a.h[j] = (_Float16)val;
      }
      Bw[nt][kt] = a.v;
    }
  }
}

template<bool XW>
static __device__ __forceinline__ void load_Ax(H8 Ax[3], const float* x, const u32* xwg,
                                               int g, int t, int c, int quad, int l){
  if constexpr (XW){
    const u32* xb = xwg + (u64)t*768ull;
    #pragma unroll
    for (int kt = 0; kt < 3; ++kt)
      Ax[kt].u4 = *(const v4u*)(xb + kt*256 + l*4);
  } else {
    const float* xb = x + ((u64)(g*16 + c)*1024ull + (u64)t)*88ull;
    #pragma unroll
    for (int kt = 0; kt < 3; ++kt){
      if (kt == 2 && quad == 3){ Ax[kt].q[0] = 0; Ax[kt].q[1] = 0; }
      else {
        const int k0 = kt*32 + quad*8;
        v4f f0 = *(const v4f*)(xb + k0);
        v4f f1 = *(const v4f*)(xb + k0 + 4);
        #pragma unroll
        for (int j = 0; j < 4; ++j){ Ax[kt].h[j] = (_Float16)f0[j]; Ax[kt].h[j+4] = (_Float16)f1[j]; }
      }
    }
  }
}

// Gate nonlinearity + emit h: local half -> LDS, half-tile -> peer (L2 + MALL).
static __device__ __forceinline__ void emit_h(const v4f acc[4], const float bb[4], float cst[4],
                                              _Float16* dstbuf, u32* hx_slot, u32 tag,
                                              int v, int c, int quad, int wcol){
  #pragma unroll
  for (int r = 0; r < 4; ++r){
    const float gi = acc[0][r] + bb[0];
    const float gf = acc[1][r] + bb[1];
    const float gg = acc[2][r] + bb[2];
    const float go = acc[3][r] + bb[3];
    const float cn = fsig(gf)*cst[r] + fsig(gi)*ftanh(gg);
    cst[r] = cn;
    const float hn = fsig(go)*ftanh(cn);
    const int row = quad*4 + r;
    const int ab = (row*512 + wcol*2) ^ ((row&7)<<4);
    *(_Float16*)((char*)dstbuf + ab) = (_Float16)hn;
    st_x2(hx_slot + (row*128 + v*16 + c), f2tag(hn, tag));
  }
}

// One-shot x -> f16 A-fragment layout.
__global__ __launch_bounds__(256) void xconv(const float* __restrict__ x, u32* __restrict__ xw){
  const int flat = (int)blockIdx.x*256 + (int)threadIdx.x;
  const int l  = flat & 63;
  const int f2 = flat >> 6;
  const int kt = f2 % 3;
  const int f3 = f2 / 3;
  const int t  = f3 & 1023;
  const int g  = f3 >> 10;
  const int c = l & 15, quad = l >> 4;
  H8 a;
  if (kt == 2 && quad == 3){ a.q[0] = 0; a.q[1] = 0; }
  else {
    const float* xb = x + ((u64)(g*16 + c)*1024ull + (u64)t)*88ull + kt*32 + quad*8;
    v4f f0 = *(const v4f*)xb;
    v4f f1 = *(const v4f*)(xb + 4);
    #pragma unroll
    for (int j = 0; j < 4; ++j){ a.h[j] = (_Float16)f0[j]; a.h[j+4] = (_Float16)f1[j]; }
  }
  *(v4u*)(xw + (u64)flat*4ull) = a.u4;
}

template<bool XW>
__global__ __launch_bounds__(512, 2) void lstm_ae(
    const float* __restrict__ x,
    const float* __restrict__ Wih_e, const float* __restrict__ Whh_e,
    const float* __restrict__ bih_e, const float* __restrict__ bhh_e,
    const float* __restrict__ Wih_d, const float* __restrict__ Whh_d,
    const float* __restrict__ bih_d, const float* __restrict__ bhh_d,
    const float* __restrict__ W_lat, const float* __restrict__ b_lat,
    const float* __restrict__ W_decinit, const float* __restrict__ b_decinit,
    const float* __restrict__ W_out, const float* __restrict__ b_out,
    float* __restrict__ dout, char* __restrict__ ws)
{
  const int tid = (int)threadIdx.x;
  const int v = tid >> 6, l = tid & 63;
  const int c = l & 15, quad = l >> 4;
  const int bid = (int)blockIdx.x;
  const int g = bid & 7, hf = bid >> 3;   // pair {g, g+8}: same XCD under round-robin
  const int wcol = hf*128 + v*16 + c;
  const int kL = hf*4;
  const int kR = 4 - hf*4;

  u32* wsu = (u32*)ws;
  u32* hx_w       = wsu + (u64)((g*2 + hf)*2)     * 2048ull;
  const u32* hx_r = wsu + (u64)((g*2 + (1-hf))*2) * 2048ull;
  const u32* xwg  = wsu + XW_OFF_U32 + (u64)g * XW_U32_PER_G;

  const int srow  = tid >> 5;
  const int scol  = (1-hf)*128 + (tid & 31)*4;
  const int sbyte = (srow*512 + scol*2) ^ ((srow&7)<<4);

  __shared__ _Float16 h2[2][4096];
  __shared__ _Float16 xp[2048];
  __shared__ v4u woutlds[3072];

  // ---- prologue: W_out -> LDS frags ----
  #pragma unroll
  for (int i = 0; i < 6; ++i){
    const int fid = v*6 + i;
    const int nt = fid >> 3, kt = fid & 7;
    const int n = nt*16 + c, k0 = kt*32 + quad*8;
    H8 a;
    #pragma unroll
    for (int j = 0; j < 8; ++j)
      a.h[j] = (n < 88) ? (_Float16)W_out[n*256 + k0 + j] : (_Float16)0.f;
    woutlds[fid*64 + l] = a.u4;
  }

  v8h Bw[4][11];
  build_Bw(Bw, Wih_e, Whh_e, wcol, quad, hf);
  float bb[4];
  #pragma unroll
  for (int nt = 0; nt < 4; ++nt) bb[nt] = bih_e[nt*256 + wcol] + bhh_e[nt*256 + wcol];
  float cst[4] = {0.f, 0.f, 0.f, 0.f};
  __syncthreads();

  // ================= encoder =================
  {
    H8 Ax[3];
    load_Ax<XW>(Ax, x, xwg, g, 0, c, quad, l);
    v4f acc[4];
    #pragma unroll
    for (int nt = 0; nt < 4; ++nt) acc[nt] = (v4f){0.f,0.f,0.f,0.f};
    #pragma unroll
    for (int kt = 0; kt < 3; ++kt)
      #pragma unroll
      for (int nt = 0; nt < 4; ++nt)
        acc[nt] = __builtin_amdgcn_mfma_f32_16x16x32_f16(Ax[kt].v, Bw[nt][kt], acc[nt], 0,0,0);
    emit_h(acc, bb, cst, h2[0], hx_w, ENC_TAG(0), v, c, quad, wcol);
    __syncthreads();
  }

  // x-contribution for t=1, precomputed (pipelined accumulator set)
  v4f accx[4];
  {
    H8 Ax[3];
    load_Ax<XW>(Ax, x, xwg, g, 1, c, quad, l);
    #pragma unroll
    for (int nt = 0; nt < 4; ++nt) accx[nt] = (v4f){0.f,0.f,0.f,0.f};
    #pragma unroll
    for (int kt = 0; kt < 3; ++kt)
      #pragma unroll
      for (int nt = 0; nt < 4; ++nt)
        accx[nt] = __builtin_amdgcn_mfma_f32_16x16x32_f16(Ax[kt].v, Bw[nt][kt], accx[nt], 0,0,0);
  }

  #pragma unroll 1
  for (int t = 1; t < 1024; ++t){
    const int cur = (t-1)&1, nxt = t&1;
    const u32* pp = hx_r + (u64)cur*2048ull + tid*4;
    v4u q; poll_issue(pp, q);

    v4f acc[4];
    #pragma unroll
    for (int nt = 0; nt < 4; ++nt) acc[nt] = accx[nt];

    H8 AhL[4];
    #pragma unroll
    for (int i = 0; i < 4; ++i) AhL[i].u4 = frag_h(h2[cur], c, (kL+i)*32 + quad*8);
    #pragma unroll
    for (int i = 0; i < 4; ++i)
      #pragma unroll
      for (int nt = 0; nt < 4; ++nt)
        acc[nt] = __builtin_amdgcn_mfma_f32_16x16x32_f16(AhL[i].v, Bw[nt][3+i], acc[nt], 0,0,0);

    // next step's x-contribution in the poll shadow
    if (t < 1023){
      H8 Ax[3];
      load_Ax<XW>(Ax, x, xwg, g, t+1, c, quad, l);
      #pragma unroll
      for (int nt = 0; nt < 4; ++nt) accx[nt] = (v4f){0.f,0.f,0.f,0.f};
      #pragma unroll
      for (int kt = 0; kt < 3; ++kt)
        #pragma unroll
        for (int nt = 0; nt < 4; ++nt)
          accx[nt] = __builtin_amdgcn_mfma_f32_16x16x32_f16(Ax[kt].v, Bw[nt][kt], accx[nt], 0,0,0);
    }

    poll_finish(pp, ENC_TAG(t-1), q, h2[cur], sbyte);
    __syncthreads();

    H8 AhR[4];
    #pragma unroll
    for (int i = 0; i < 4; ++i) AhR[i].u4 = frag_h(h2[cur], c, (kR+i)*32 + quad*8);
    #pragma unroll
    for (int i = 0; i < 4; ++i)
      #pragma unroll
      for (int nt = 0; nt < 4; ++nt)
        acc[nt] = __builtin_amdgcn_mfma_f32_16x16x32_f16(AhR[i].v, Bw[nt][7+i], acc[nt], 0,0,0);

    emit_h(acc, bb, cst, h2[nxt], hx_w + (u64)nxt*2048ull, ENC_TAG(t), v, c, quad, wcol);
    __syncthreads();
  }

  // ---- stage remote half of h(1023) ----
  {
    const u32* pp = hx_r + 2048ull + tid*4;
    v4u q; poll_issue(pp, q);
    poll_finish(pp, ENC_TAG(1023), q, h2[1], sbyte);
    __syncthreads();
  }

  // ---- latent: z = h_n @ W_lat.T + b_lat (both WGs, redundant) ----
  {
    H8 AhL[4], AhR[4];
    #pragma unroll
    for (int i = 0; i < 4; ++i) AhL[i].u4 = frag_h(h2[1], c, (kL+i)*32 + quad*8);
    #pragma unroll
    for (int i = 0; i < 4; ++i) AhR[i].u4 = frag_h(h2[1], c, (kR+i)*32 + quad*8);
    const int n = v*16 + c;
    v4f zacc = (v4f){0.f,0.f,0.f,0.f};
    #pragma unroll
    for (int i = 0; i < 4; ++i){
      H8 b; const int k0 = (kL+i)*32 + quad*8;
      #pragma unroll
      for (int j = 0; j < 8; ++j) b.h[j] = (_Float16)W_lat[n*256 + k0 + j];
      zacc = __builtin_amdgcn_mfma_f32_16x16x32_f16(AhL[i].v, b.v, zacc, 0,0,0);
    }
    #pragma unroll
    for (int i = 0; i < 4; ++i){
      H8 b; const int k0 = (kR+i)*32 + quad*8;
      #pragma unroll
      for (int j = 0; j < 8; ++j) b.h[j] = (_Float16)W_lat[n*256 + k0 + j];
      zacc = __builtin_amdgcn_mfma_f32_16x16x32_f16(AhR[i].v, b.v, zacc, 0,0,0);
    }
    const float bl = b_lat[n];
    #pragma unroll
    for (int r = 0; r < 4; ++r){
      const int m = quad*4 + r;
      const float zv = zacc[r] + bl;
      if (hf == 0)
        __builtin_nontemporal_store(zv, dout + 11534336ull + (u64)(g*16 + m)*128ull + n);
      const int ab = (m*256 + n*2) ^ ((m&7)<<4);
      *(_Float16*)((char*)xp + ab) = (_Float16)zv;
    }
    __syncthreads();
  }

  // ---- decoder init: h0 = z @ W_decinit.T + b_decinit (full h0, no exchange) ----
  {
    H8 Az[4];
    #pragma unroll
    for (int kt = 0; kt < 4; ++kt) Az[kt].u4 = frag_x(xp, c, kt*32 + quad*8);
    #pragma unroll
    for (int half = 0; half < 2; ++half){
      const int n = half*128 + v*16 + c;
      v4f da = (v4f){0.f,0.f,0.f,0.f};
      #pragma unroll
      for (int kt = 0; kt < 4; ++kt){
        H8 b; const int k0 = kt*32 + quad*8;
        #pragma unroll
        for (int j = 0; j < 8; ++j) b.h[j] = (_Float16)W_decinit[n*128 + k0 + j];
        da = __builtin_amdgcn_mfma_f32_16x16x32_f16(Az[kt].v, b.v, da, 0,0,0);
      }
      const float bdi = b_decinit[n];
      #pragma unroll
      for (int r = 0; r < 4; ++r){
        const int row = quad*4 + r;
        const int ab = (row*512 + n*2) ^ ((row&7)<<4);
        *(_Float16*)((char*)h2[1] + ab) = (_Float16)(da[r] + bdi);
      }
    }
    __syncthreads();
  }

  // ---- switch to decoder weights ----
  build_Bw(Bw, Wih_d, Whh_d, wcol, quad, hf);
  #pragma unroll
  for (int nt = 0; nt < 4; ++nt) bb[nt] = bih_d[nt*256 + wcol] + bhh_d[nt*256 + wcol];
  float bo = 0.f;
  if (v < 6){ const int n = v*16 + c; bo = (n < 88) ? b_out[n] : 0.f; }
  #pragma unroll
  for (int r = 0; r < 4; ++r) cst[r] = 0.f;

  // ================= decoder =================
  #pragma unroll 1
  for (int t = 0; t < 1024; ++t){
    const int cur = (t+1)&1, nxt = t&1;
    const u32* pp = hx_r + (u64)cur*2048ull + tid*4;
    v4u q;
    if (t > 0) poll_issue(pp, q);

    H8 AhL[4], AhR[4];
    v4f acc[4];
    #pragma unroll
    for (int nt = 0; nt < 4; ++nt) acc[nt] = (v4f){0.f,0.f,0.f,0.f};
    #pragma unroll
    for (int i = 0; i < 4; ++i) AhL[i].u4 = frag_h(h2[cur], c, (kL+i)*32 + quad*8);
    #pragma unroll
    for (int i = 0; i < 4; ++i)
      #pragma unroll
      for (int nt = 0; nt < 4; ++nt)
        acc[nt] = __builtin_amdgcn_mfma_f32_16x16x32_f16(AhL[i].v, Bw[nt][3+i], acc[nt], 0,0,0);

    // pred(t-1) local-half contribution: only needs the local h in LDS,
    // so it runs inside the poll shadow
    v4f pacc = (v4f){0.f,0.f,0.f,0.f};
    if (t > 0 && v < 6){
      #pragma unroll
      for (int i = 0; i < 4; ++i){
        H8 b; b.u4 = woutlds[(v*8 + kL + i)*64 + l];
        pacc = __builtin_amdgcn_mfma_f32_16x16x32_f16(AhL[i].v, b.v, pacc, 0,0,0);
      }
    }

    if (t > 0) poll_finish(pp, DEC_TAG(t-1), q, h2[cur], sbyte);
    __syncthreads();

    #pragma unroll
    for (int i = 0; i < 4; ++i) AhR[i].u4 = frag_h(h2[cur], c, (kR+i)*32 + quad*8);
    #pragma unroll
    for (int i = 0; i < 4; ++i)
      #pragma unroll
      for (int nt = 0; nt < 4; ++nt)
        acc[nt] = __builtin_amdgcn_mfma_f32_16x16x32_f16(AhR[i].v, Bw[nt][7+i], acc[nt], 0,0,0);

    if (t > 0 && v < 6){
      #pragma unroll
      for (int i = 0; i < 4; ++i){
        H8 b; b.u4 = woutlds[(v*8 + kR + i)*64 + l];
        pacc = __builtin_amdgcn_mfma_f32_16x16x32_f16(AhR[i].v, b.v, pacc, 0,0,0);
      }
      const int n = v*16 + c;
      #pragma unroll
      for (int r = 0; r < 4; ++r){
        const float pv = fsig(pacc[r] + bo);
        const int m = quad*4 + r;
        const int ab = (m*256 + n*2) ^ ((m&7)<<4);
        *(_Float16*)((char*)xp + ab) = (_Float16)pv;
        if (hf == 0 && n < 88)
          __builtin_nontemporal_store(pv,
            dout + ((u64)(g*16 + m)*1024ull + (u64)(t-1))*88ull + n);
      }
    }
    __syncthreads();

    if (t > 0){
      H8 Ap[3];
      #pragma unroll
      for (int kt = 0; kt < 3; ++kt) Ap[kt].u4 = frag_x(xp, c, kt*32 + quad*8);
      #pragma unroll
      for (int kt = 0; kt < 3; ++kt)
        #pragma unroll
        for (int nt = 0; nt < 4; ++nt)
          acc[nt] = __builtin_amdgcn_mfma_f32_16x16x32_f16(Ap[kt].v, Bw[nt][kt], acc[nt], 0,0,0);
    }

    emit_h(acc, bb, cst, h2[nxt], hx_w + (u64)nxt*2048ull, DEC_TAG(t), v, c, quad, wcol);
    __syncthreads();
  }

  // ---- tail: pred(1023) -> output row 1023 ----
  {
    const u32* pp = hx_r + 2048ull + tid*4;
    v4u q; poll_issue(pp, q);
    poll_finish(pp, DEC_TAG(1023), q, h2[1], sbyte);
    __syncthreads();
    if (hf == 0 && v < 6){
      const int n = v*16 + c;
      v4f pacc = (v4f){0.f,0.f,0.f,0.f};
      #pragma unroll
      for (int i = 0; i < 4; ++i){
        H8 a; a.u4 = frag_h(h2[1], c, (kL+i)*32 + quad*8);
        H8 b; b.u4 = woutlds[(v*8 + kL + i)*64 + l];
        pacc = __builtin_amdgcn_mfma_f32_16x16x32_f16(a.v, b.v, pacc, 0,0,0);
      }
      #pragma unroll
      for (int i = 0; i < 4; ++i){
        H8 a; a.u4 = frag_h(h2[1], c, (kR+i)*32 + quad*8);
        H8 b; b.u4 = woutlds[(v*8 + kR + i)*64 + l];
        pacc = __builtin_amdgcn_mfma_f32_16x16x32_f16(a.v, b.v, pacc, 0,0,0);
      }
      if (n < 88){
        #pragma unroll
        for (int r = 0; r < 4; ++r){
          const float pv = fsig(pacc[r] + bo);
          const int m = quad*4 + r;
          __builtin_nontemporal_store(pv,
            dout + ((u64)(g*16 + m)*1024ull + 1023ull)*88ull + n);
        }
      }
    }
  }
}

extern "C" void kernel_launch(void* const* d_in, const int* in_sizes, int n_in,
                              void* d_out, int out_size, void* d_ws, size_t ws_size,
                              hipStream_t stream){
  (void)in_sizes; (void)n_in; (void)out_size;
  const bool xw_ok = ws_size >= WS_NEED;
  if (xw_ok){
    hipLaunchKernelGGL(xconv, dim3(6144), dim3(256), 0, stream,
                       (const float*)d_in[0], (u32*)d_ws + XW_OFF_U32);
    hipLaunchKernelGGL((lstm_ae<true>), dim3(16), dim3(512), 0, stream,
      (const float*)d_in[0],  (const float*)d_in[1],  (const float*)d_in[2],
      (const float*)d_in[3],  (const float*)d_in[4],  (const float*)d_in[5],
      (const float*)d_in[6],  (const float*)d_in[7],  (const float*)d_in[8],
      (const float*)d_in[9],  (const float*)d_in[10], (const float*)d_in[11],
      (const float*)d_in[12], (const float*)d_in[13], (const float*)d_in[14],
      (float*)d_out, (char*)d_ws);
  } else {
    hipLaunchKernelGGL((lstm_ae<false>), dim3(16), dim3(512), 0, stream,
      (const float*)d_in[0],  (const float*)d_in[1],  (const float*)d_in[2],
      (const float*)d_in[3],  (const float*)d_in[4],  (const float*)d_in[5],
      (const float*)d_in[6],  (const float*)d_in[7],  (const float*)d_in[8],
      (const float*)d_in[9],  (const float*)d_in[10], (const float*)d_in[11],
      (const float*)d_in[12], (const float*)d_in[13], (const float*)d_in[14],
      (float*)d_out, (char*)d_ws);
  }
}

// Round 3
// 6190.668 us; speedup vs baseline: 2.2134x; 2.2134x over previous
//
#include <hip/hip_runtime.h>

// Persistent-kernel LSTM autoencoder for MI355X — round 6.
// Structure: 8 groups x 2 WGs x 8 waves, register-resident weights, LDS-staged
// halves, tagged-word MALL exchange (sc0 sc1 only — r5's sc0 fast path reverted:
// stale-L2 polls made it 1.76x slower). New this round: the exchange buffer is
// COLUMN-MAJOR (word = col*16 + row), so each thread's 4 h-values are 4
// consecutive words -> ONE global_store_dwordx4 per thread, 1KB contiguous per
// wave (8 store instrs/WG/step vs 32 scattered dword stores). Poll loop is
// tight (no sleep on fast path). Decoder gains a 3rd barrier fixing the latent
// emit->read race; r5's pipelined x-MFMAs and hoisted local-pred are kept.

typedef unsigned int u32;
typedef unsigned long long u64;
typedef unsigned short u16;

typedef _Float16 v8h __attribute__((ext_vector_type(8)));
typedef float    v4f __attribute__((ext_vector_type(4)));
typedef u32      v4u __attribute__((ext_vector_type(4)));

union H8 { v8h v; u64 q[2]; v4u u4; u32 d[4]; _Float16 h[8]; u16 s[8]; };

#define ENC_TAG(t) (0x4000u + (u32)(t))
#define DEC_TAG(t) (0x4800u + (u32)(t))
#define XW_OFF_U32   65536ull
#define XW_U32_PER_G 786432ull
#define WS_NEED ((XW_OFF_U32 + 8ull*XW_U32_PER_G) * 4ull)

static __device__ __forceinline__ float fsig(float x){
  return __builtin_amdgcn_rcpf(1.f + __builtin_amdgcn_exp2f(-1.4426950408889634f*x));
}
static __device__ __forceinline__ float ftanh(float x){
  return 1.f - 2.f*__builtin_amdgcn_rcpf(1.f + __builtin_amdgcn_exp2f(2.8853900817779268f*x));
}
static __device__ __forceinline__ u32 f2tag(float f, u32 tag){
  union{ _Float16 h; u16 b; } u; u.h = (_Float16)f;
  return (tag << 16) | (u32)u.b;
}

static __device__ __forceinline__ void st_pk4(u32* p, v4u val){
  asm volatile("global_store_dwordx4 %0, %1, off sc0 sc1" :: "v"(p), "v"(val) : "memory");
}
static __device__ __forceinline__ void poll_issue(const u32* p, v4u& q){
  asm volatile("global_load_dwordx4 %0, %1, off sc0 sc1" : "=v"(q) : "v"(p) : "memory");
}
static __device__ __forceinline__ void poll_sc01(const u32* p, v4u& q){
  asm volatile("global_load_dwordx4 %0, %1, off sc0 sc1\n\ts_waitcnt vmcnt(0)"
               : "=v"(q) : "v"(p) : "memory");
}
static __device__ __forceinline__ void poll_wait(v4u& q){
  asm volatile("s_waitcnt vmcnt(0)" : "+v"(q) :: "memory");
}

// Wait for this thread's 4 tagged words (col = tid>>2, rows rbase..rbase+3 of
// the remote half), then stage the f16 payloads into the swizzled LDS h tile.
static __device__ __forceinline__ void poll_finish(const u32* p, u32 tag, v4u& q,
                                                   _Float16* dstbuf, int rbase, int scol){
  const u32 tm = tag << 16;
  poll_wait(q);
  u32 it = 0;
  for(;;){
    u32 bad = (q[0]^tm)|(q[1]^tm)|(q[2]^tm)|(q[3]^tm);
    if (__all((bad & 0xFFFF0000u) == 0)) break;
    if ((++it & 15u) == 0u) __builtin_amdgcn_s_sleep(1);
    poll_sc01(p, q);
  }
  #pragma unroll
  for (int j = 0; j < 4; ++j){
    const int row = rbase + j;
    const int ab = (row*512 + scol*2) ^ ((row&7)<<4);
    *(u16*)((char*)dstbuf + ab) = (u16)(q[j] & 0xFFFFu);
  }
}

// LDS A-fragment reads, XOR-swizzled.
static __device__ __forceinline__ v4u frag_h(const _Float16* b, int row, int colh){
  const int a = (row*512 + colh*2) ^ ((row&7)<<4);
  return *(const v4u*)((const char*)b + a);
}
static __device__ __forceinline__ v4u frag_x(const _Float16* b, int row, int colh){
  const int a = (row*256 + colh*2) ^ ((row&7)<<4);
  return *(const v4u*)((const char*)b + a);
}

// B-frags: kt 0..2 = input (88+pad), kt 3..6 = LOCAL h half, kt 7..10 = REMOTE.
static __device__ __forceinline__ void build_Bw(v8h Bw[4][11], const float* Wih,
                                                const float* Whh, int wcol, int quad, int hf){
  #pragma unroll
  for (int nt = 0; nt < 4; ++nt){
    const int n = nt*256 + wcol;
    #pragma unroll
    for (int kt = 0; kt < 11; ++kt){
      H8 a;
      #pragma unroll
      for (int j = 0; j < 8; ++j){
        float val;
        if (kt < 3){
          const int k = kt*32 + quad*8 + j;
          val = (k < 88) ? Wih[n*88 + k] : 0.f;
        } else {
          const int base = (kt < 7) ? (hf*128 + (kt-3)*32) : ((1-hf)*128 + (kt-7)*32);
          val = Whh[n*256 + base + quad*8 + j];
        }
        a.h[j] = (_Float16)val;
      }
      Bw[nt][kt] = a.v;
    }
  }
}

template<bool XW>
static __device__ __forceinline__ void load_Ax(H8 Ax[3], const float* x, const u32* xwg,
                                               int g, int t, int c, int quad, int l){
  if constexpr (XW){
    const u32* xb = xwg + (u64)t*768ull;
    #pragma unroll
    for (int kt = 0; kt < 3; ++kt)
      Ax[kt].u4 = *(const v4u*)(xb + kt*256 + l*4);
  } else {
    const float* xb = x + ((u64)(g*16 + c)*1024ull + (u64)t)*88ull;
    #pragma unroll
    for (int kt = 0; kt < 3; ++kt){
      if (kt == 2 && quad == 3){ Ax[kt].q[0] = 0; Ax[kt].q[1] = 0; }
      else {
        const int k0 = kt*32 + quad*8;
        v4f f0 = *(const v4f*)(xb + k0);
        v4f f1 = *(const v4f*)(xb + k0 + 4);
        #pragma unroll
        for (int j = 0; j < 4; ++j){ Ax[kt].h[j] = (_Float16)f0[j]; Ax[kt].h[j+4] = (_Float16)f1[j]; }
      }
    }
  }
}

// Gate nonlinearity + emit h: local half -> LDS; the thread's 4 tagged words
// (one column, rows quad*4..+3) -> ONE dwordx4 to the peer, column-major
// layout so each wave's 64 lanes store a contiguous 1KB block.
static __device__ __forceinline__ void emit_h(const v4f acc[4], const float bb[4], float cst[4],
                                              _Float16* dstbuf, u32* hx_slot, u32 tag,
                                              int c, int quad, int wcol){
  v4u pk;
  #pragma unroll
  for (int r = 0; r < 4; ++r){
    const float gi = acc[0][r] + bb[0];
    const float gf = acc[1][r] + bb[1];
    const float gg = acc[2][r] + bb[2];
    const float go = acc[3][r] + bb[3];
    const float cn = fsig(gf)*cst[r] + fsig(gi)*ftanh(gg);
    cst[r] = cn;
    const float hn = fsig(go)*ftanh(cn);
    const int row = quad*4 + r;
    const int ab = (row*512 + wcol*2) ^ ((row&7)<<4);
    *(_Float16*)((char*)dstbuf + ab) = (_Float16)hn;
    pk[r] = f2tag(hn, tag);
  }
  st_pk4(hx_slot + ((wcol & 127)*16 + quad*4), pk);
}

// One-shot x -> f16 A-fragment layout.
__global__ __launch_bounds__(256) void xconv(const float* __restrict__ x, u32* __restrict__ xw){
  const int flat = (int)blockIdx.x*256 + (int)threadIdx.x;
  const int l  = flat & 63;
  const int f2 = flat >> 6;
  const int kt = f2 % 3;
  const int f3 = f2 / 3;
  const int t  = f3 & 1023;
  const int g  = f3 >> 10;
  const int c = l & 15, quad = l >> 4;
  H8 a;
  if (kt == 2 && quad == 3){ a.q[0] = 0; a.q[1] = 0; }
  else {
    const float* xb = x + ((u64)(g*16 + c)*1024ull + (u64)t)*88ull + kt*32 + quad*8;
    v4f f0 = *(const v4f*)xb;
    v4f f1 = *(const v4f*)(xb + 4);
    #pragma unroll
    for (int j = 0; j < 4; ++j){ a.h[j] = (_Float16)f0[j]; a.h[j+4] = (_Float16)f1[j]; }
  }
  *(v4u*)(xw + (u64)flat*4ull) = a.u4;
}

template<bool XW>
__global__ __launch_bounds__(512, 2) void lstm_ae(
    const float* __restrict__ x,
    const float* __restrict__ Wih_e, const float* __restrict__ Whh_e,
    const float* __restrict__ bih_e, const float* __restrict__ bhh_e,
    const float* __restrict__ Wih_d, const float* __restrict__ Whh_d,
    const float* __restrict__ bih_d, const float* __restrict__ bhh_d,
    const float* __restrict__ W_lat, const float* __restrict__ b_lat,
    const float* __restrict__ W_decinit, const float* __restrict__ b_decinit,
    const float* __restrict__ W_out, const float* __restrict__ b_out,
    float* __restrict__ dout, char* __restrict__ ws)
{
  const int tid = (int)threadIdx.x;
  const int v = tid >> 6, l = tid & 63;
  const int c = l & 15, quad = l >> 4;
  const int bid = (int)blockIdx.x;
  const int g = bid & 7, hf = bid >> 3;
  const int wcol = hf*128 + v*16 + c;
  const int kL = hf*4;
  const int kR = 4 - hf*4;

  u32* wsu = (u32*)ws;
  u32* hx_w       = wsu + (u64)((g*2 + hf)*2)     * 2048ull;
  const u32* hx_r = wsu + (u64)((g*2 + (1-hf))*2) * 2048ull;
  const u32* xwg  = wsu + XW_OFF_U32 + (u64)g * XW_U32_PER_G;

  // Reader staging geometry (column-major exchange): col tid>>2, rows (tid&3)*4..+3.
  const int rbase = (tid & 3) * 4;
  const int scol  = (1-hf)*128 + (tid >> 2);

  __shared__ _Float16 h2[2][4096];
  __shared__ _Float16 xp[2048];
  __shared__ v4u woutlds[3072];

  // ---- prologue: W_out -> LDS frags ----
  #pragma unroll
  for (int i = 0; i < 6; ++i){
    const int fid = v*6 + i;
    const int nt = fid >> 3, kt = fid & 7;
    const int n = nt*16 + c, k0 = kt*32 + quad*8;
    H8 a;
    #pragma unroll
    for (int j = 0; j < 8; ++j)
      a.h[j] = (n < 88) ? (_Float16)W_out[n*256 + k0 + j] : (_Float16)0.f;
    woutlds[fid*64 + l] = a.u4;
  }

  v8h Bw[4][11];
  build_Bw(Bw, Wih_e, Whh_e, wcol, quad, hf);
  float bb[4];
  #pragma unroll
  for (int nt = 0; nt < 4; ++nt) bb[nt] = bih_e[nt*256 + wcol] + bhh_e[nt*256 + wcol];
  float cst[4] = {0.f, 0.f, 0.f, 0.f};
  __syncthreads();

  // ================= encoder =================
  {
    H8 Ax[3];
    load_Ax<XW>(Ax, x, xwg, g, 0, c, quad, l);
    v4f acc[4];
    #pragma unroll
    for (int nt = 0; nt < 4; ++nt) acc[nt] = (v4f){0.f,0.f,0.f,0.f};
    #pragma unroll
    for (int kt = 0; kt < 3; ++kt)
      #pragma unroll
      for (int nt = 0; nt < 4; ++nt)
        acc[nt] = __builtin_amdgcn_mfma_f32_16x16x32_f16(Ax[kt].v, Bw[nt][kt], acc[nt], 0,0,0);
    emit_h(acc, bb, cst, h2[0], hx_w, ENC_TAG(0), c, quad, wcol);
    __syncthreads();
  }

  // x-contribution for t=1, precomputed (pipelined accumulator set)
  v4f accx[4];
  {
    H8 Ax[3];
    load_Ax<XW>(Ax, x, xwg, g, 1, c, quad, l);
    #pragma unroll
    for (int nt = 0; nt < 4; ++nt) accx[nt] = (v4f){0.f,0.f,0.f,0.f};
    #pragma unroll
    for (int kt = 0; kt < 3; ++kt)
      #pragma unroll
      for (int nt = 0; nt < 4; ++nt)
        accx[nt] = __builtin_amdgcn_mfma_f32_16x16x32_f16(Ax[kt].v, Bw[nt][kt], accx[nt], 0,0,0);
  }

  #pragma unroll 1
  for (int t = 1; t < 1024; ++t){
    const int cur = (t-1)&1, nxt = t&1;
    const u32* pp = hx_r + (u64)cur*2048ull + tid*4;
    v4u q; poll_issue(pp, q);

    v4f acc[4];
    #pragma unroll
    for (int nt = 0; nt < 4; ++nt) acc[nt] = accx[nt];

    H8 AhL[4];
    #pragma unroll
    for (int i = 0; i < 4; ++i) AhL[i].u4 = frag_h(h2[cur], c, (kL+i)*32 + quad*8);
    #pragma unroll
    for (int i = 0; i < 4; ++i)
      #pragma unroll
      for (int nt = 0; nt < 4; ++nt)
        acc[nt] = __builtin_amdgcn_mfma_f32_16x16x32_f16(AhL[i].v, Bw[nt][3+i], acc[nt], 0,0,0);

    // next step's x-contribution in the poll shadow
    if (t < 1023){
      H8 Ax[3];
      load_Ax<XW>(Ax, x, xwg, g, t+1, c, quad, l);
      #pragma unroll
      for (int nt = 0; nt < 4; ++nt) accx[nt] = (v4f){0.f,0.f,0.f,0.f};
      #pragma unroll
      for (int kt = 0; kt < 3; ++kt)
        #pragma unroll
        for (int nt = 0; nt < 4; ++nt)
          accx[nt] = __builtin_amdgcn_mfma_f32_16x16x32_f16(Ax[kt].v, Bw[nt][kt], accx[nt], 0,0,0);
    }

    poll_finish(pp, ENC_TAG(t-1), q, h2[cur], rbase, scol);
    __syncthreads();

    H8 AhR[4];
    #pragma unroll
    for (int i = 0; i < 4; ++i) AhR[i].u4 = frag_h(h2[cur], c, (kR+i)*32 + quad*8);
    #pragma unroll
    for (int i = 0; i < 4; ++i)
      #pragma unroll
      for (int nt = 0; nt < 4; ++nt)
        acc[nt] = __builtin_amdgcn_mfma_f32_16x16x32_f16(AhR[i].v, Bw[nt][7+i], acc[nt], 0,0,0);

    emit_h(acc, bb, cst, h2[nxt], hx_w + (u64)nxt*2048ull, ENC_TAG(t), c, quad, wcol);
    __syncthreads();
  }

  // ---- stage remote half of h(1023) ----
  {
    const u32* pp = hx_r + 2048ull + tid*4;
    v4u q; poll_issue(pp, q);
    poll_finish(pp, ENC_TAG(1023), q, h2[1], rbase, scol);
    __syncthreads();
  }

  // ---- latent: z = h_n @ W_lat.T + b_lat (both WGs, redundant) ----
  {
    H8 AhL[4], AhR[4];
    #pragma unroll
    for (int i = 0; i < 4; ++i) AhL[i].u4 = frag_h(h2[1], c, (kL+i)*32 + quad*8);
    #pragma unroll
    for (int i = 0; i < 4; ++i) AhR[i].u4 = frag_h(h2[1], c, (kR+i)*32 + quad*8);
    const int n = v*16 + c;
    v4f zacc = (v4f){0.f,0.f,0.f,0.f};
    #pragma unroll
    for (int i = 0; i < 4; ++i){
      H8 b; const int k0 = (kL+i)*32 + quad*8;
      #pragma unroll
      for (int j = 0; j < 8; ++j) b.h[j] = (_Float16)W_lat[n*256 + k0 + j];
      zacc = __builtin_amdgcn_mfma_f32_16x16x32_f16(AhL[i].v, b.v, zacc, 0,0,0);
    }
    #pragma unroll
    for (int i = 0; i < 4; ++i){
      H8 b; const int k0 = (kR+i)*32 + quad*8;
      #pragma unroll
      for (int j = 0; j < 8; ++j) b.h[j] = (_Float16)W_lat[n*256 + k0 + j];
      zacc = __builtin_amdgcn_mfma_f32_16x16x32_f16(AhR[i].v, b.v, zacc, 0,0,0);
    }
    const float bl = b_lat[n];
    #pragma unroll
    for (int r = 0; r < 4; ++r){
      const int m = quad*4 + r;
      const float zv = zacc[r] + bl;
      if (hf == 0)
        __builtin_nontemporal_store(zv, dout + 11534336ull + (u64)(g*16 + m)*128ull + n);
      const int ab = (m*256 + n*2) ^ ((m&7)<<4);
      *(_Float16*)((char*)xp + ab) = (_Float16)zv;
    }
    __syncthreads();
  }

  // ---- decoder init: h0 = z @ W_decinit.T + b_decinit (full h0, no exchange) ----
  {
    H8 Az[4];
    #pragma unroll
    for (int kt = 0; kt < 4; ++kt) Az[kt].u4 = frag_x(xp, c, kt*32 + quad*8);
    #pragma unroll
    for (int half = 0; half < 2; ++half){
      const int n = half*128 + v*16 + c;
      v4f da = (v4f){0.f,0.f,0.f,0.f};
      #pragma unroll
      for (int kt = 0; kt < 4; ++kt){
        H8 b; const int k0 = kt*32 + quad*8;
        #pragma unroll
        for (int j = 0; j < 8; ++j) b.h[j] = (_Float16)W_decinit[n*128 + k0 + j];
        da = __builtin_amdgcn_mfma_f32_16x16x32_f16(Az[kt].v, b.v, da, 0,0,0);
      }
      const float bdi = b_decinit[n];
      #pragma unroll
      for (int r = 0; r < 4; ++r){
        const int row = quad*4 + r;
        const int ab = (row*512 + n*2) ^ ((row&7)<<4);
        *(_Float16*)((char*)h2[1] + ab) = (_Float16)(da[r] + bdi);
      }
    }
    __syncthreads();
  }

  // ---- switch to decoder weights ----
  build_Bw(Bw, Wih_d, Whh_d, wcol, quad, hf);
  #pragma unroll
  for (int nt = 0; nt < 4; ++nt) bb[nt] = bih_d[nt*256 + wcol] + bhh_d[nt*256 + wcol];
  float bo = 0.f;
  if (v < 6){ const int n = v*16 + c; bo = (n < 88) ? b_out[n] : 0.f; }
  #pragma unroll
  for (int r = 0; r < 4; ++r) cst[r] = 0.f;

  // ================= decoder =================
  #pragma unroll 1
  for (int t = 0; t < 1024; ++t){
    const int cur = (t+1)&1, nxt = t&1;   // t=0 reads full h0 in h2[1]
    const u32* pp = hx_r + (u64)cur*2048ull + tid*4;
    v4u q;
    if (t > 0) poll_issue(pp, q);

    H8 AhL[4], AhR[4];
    v4f acc[4];
    #pragma unroll
    for (int nt = 0; nt < 4; ++nt) acc[nt] = (v4f){0.f,0.f,0.f,0.f};
    #pragma unroll
    for (int i = 0; i < 4; ++i) AhL[i].u4 = frag_h(h2[cur], c, (kL+i)*32 + quad*8);
    #pragma unroll
    for (int i = 0; i < 4; ++i)
      #pragma unroll
      for (int nt = 0; nt < 4; ++nt)
        acc[nt] = __builtin_amdgcn_mfma_f32_16x16x32_f16(AhL[i].v, Bw[nt][3+i], acc[nt], 0,0,0);

    // pred(t-1) local-half contribution in the poll shadow
    v4f pacc = (v4f){0.f,0.f,0.f,0.f};
    if (t > 0 && v < 6){
      #pragma unroll
      for (int i = 0; i < 4; ++i){
        H8 b; b.u4 = woutlds[(v*8 + kL + i)*64 + l];
        pacc = __builtin_amdgcn_mfma_f32_16x16x32_f16(AhL[i].v, b.v, pacc, 0,0,0);
      }
    }

    if (t > 0) poll_finish(pp, DEC_TAG(t-1), q, h2[cur], rbase, scol);
    __syncthreads();

    #pragma unroll
    for (int i = 0; i < 4; ++i) AhR[i].u4 = frag_h(h2[cur], c, (kR+i)*32 + quad*8);
    #pragma unroll
    for (int i = 0; i < 4; ++i)
      #pragma unroll
      for (int nt = 0; nt < 4; ++nt)
        acc[nt] = __builtin_amdgcn_mfma_f32_16x16x32_f16(AhR[i].v, Bw[nt][7+i], acc[nt], 0,0,0);

    if (t > 0 && v < 6){
      #pragma unroll
      for (int i = 0; i < 4; ++i){
        H8 b; b.u4 = woutlds[(v*8 + kR + i)*64 + l];
        pacc = __builtin_amdgcn_mfma_f32_16x16x32_f16(AhR[i].v, b.v, pacc, 0,0,0);
      }
      const int n = v*16 + c;
      #pragma unroll
      for (int r = 0; r < 4; ++r){
        const float pv = fsig(pacc[r] + bo);
        const int m = quad*4 + r;
        const int ab = (m*256 + n*2) ^ ((m&7)<<4);
        *(_Float16*)((char*)xp + ab) = (_Float16)pv;
        if (hf == 0 && n < 88)
          __builtin_nontemporal_store(pv,
            dout + ((u64)(g*16 + m)*1024ull + (u64)(t-1))*88ull + n);
      }
    }
    __syncthreads();

    if (t > 0){
      H8 Ap[3];
      #pragma unroll
      for (int kt = 0; kt < 3; ++kt) Ap[kt].u4 = frag_x(xp, c, kt*32 + quad*8);
      #pragma unroll
      for (int kt = 0; kt < 3; ++kt)
        #pragma unroll
        for (int nt = 0; nt < 4; ++nt)
          acc[nt] = __builtin_amdgcn_mfma_f32_16x16x32_f16(Ap[kt].v, Bw[nt][kt], acc[nt], 0,0,0);
    }

    emit_h(acc, bb, cst, h2[nxt], hx_w + (u64)nxt*2048ull, DEC_TAG(t), c, quad, wcol);
    __syncthreads();   // B3: protects h2[nxt] for next iteration's AhL reads
  }

  // ---- tail: pred(1023) -> output row 1023 ----
  {
    const u32* pp = hx_r + 2048ull + tid*4;
    v4u q; poll_issue(pp, q);
    poll_finish(pp, DEC_TAG(1023), q, h2[1], rbase, scol);
    __syncthreads();
    if (hf == 0 && v < 6){
      const int n = v*16 + c;
      v4f pacc = (v4f){0.f,0.f,0.f,0.f};
      #pragma unroll
      for (int i = 0; i < 4; ++i){
        H8 a; a.u4 = frag_h(h2[1], c, (kL+i)*32 + quad*8);
        H8 b; b.u4 = woutlds[(v*8 + kL + i)*64 + l];
        pacc = __builtin_amdgcn_mfma_f32_16x16x32_f16(a.v, b.v, pacc, 0,0,0);
      }
      #pragma unroll
      for (int i = 0; i < 4; ++i){
        H8 a; a.u4 = frag_h(h2[1], c, (kR+i)*32 + quad*8);
        H8 b; b.u4 = woutlds[(v*8 + kR + i)*64 + l];
        pacc = __builtin_amdgcn_mfma_f32_16x16x32_f16(a.v, b.v, pacc, 0,0,0);
      }
      if (n < 88){
        #pragma unroll
        for (int r = 0; r < 4; ++r){
          const float pv = fsig(pacc[r] + bo);
          const int m = quad*4 + r;
          __builtin_nontemporal_store(pv,
            dout + ((u64)(g*16 + m)*1024ull + 1023ull)*88ull + n);
        }
      }
    }
  }
}

extern "C" void kernel_launch(void* const* d_in, const int* in_sizes, int n_in,
                              void* d_out, int out_size, void* d_ws, size_t ws_size,
                              hipStream_t stream){
  (void)in_sizes; (void)n_in; (void)out_size;
  const bool xw_ok = ws_size >= WS_NEED;
  if (xw_ok){
    hipLaunchKernelGGL(xconv, dim3(6144), dim3(256), 0, stream,
                       (const float*)d_in[0], (u32*)d_ws + XW_OFF_U32);
    hipLaunchKernelGGL((lstm_ae<true>), dim3(16), dim3(512), 0, stream,
      (const float*)d_in[0],  (const float*)d_in[1],  (const float*)d_in[2],
      (const float*)d_in[3],  (const float*)d_in[4],  (const float*)d_in[5],
      (const float*)d_in[6],  (const float*)d_in[7],  (const float*)d_in[8],
      (const float*)d_in[9],  (const float*)d_in[10], (const float*)d_in[11],
      (const float*)d_in[12], (const float*)d_in[13], (const float*)d_in[14],
      (float*)d_out, (char*)d_ws);
  } else {
    hipLaunchKernelGGL((lstm_ae<false>), dim3(16), dim3(512), 0, stream,
      (const float*)d_in[0],  (const float*)d_in[1],  (const float*)d_in[2],
      (const float*)d_in[3],  (const float*)d_in[4],  (const float*)d_in[5],
      (const float*)d_in[6],  (const float*)d_in[7],  (const float*)d_in[8],
      (const float*)d_in[9],  (const float*)d_in[10], (const float*)d_in[11],
      (const float*)d_in[12], (const float*)d_in[13], (const float*)d_in[14],
      (float*)d_out, (char*)d_ws);
  }
}